// Round 5
// baseline (2342.335 us; speedup 1.0000x reference)
//
#include <hip/hip_runtime.h>

#define NTH  1024
#define XLEN 368
#define NF   112

typedef short bh8 __attribute__((ext_vector_type(8)));
typedef float fv4 __attribute__((ext_vector_type(4)));

// ---- LDS layout (ushort-element offsets) ----
#define IMG_OFF 0            // 114x114 bf16 zero-halo img   [0,12996)
#define IMG_LD  114
#define X0H 12996            // xsp bf16, even-pair copy     (1024 el)
#define X1H 14020            // xsp bf16, shifted-by-1       (1024 el)
#define H1_OFF 15044         // 6 x 58 x 58 bf16 zero-halo   (20184 el)
#define TOT_E 35228          // *2 = 70456 bytes -> 2 blocks/CU

// time-aliased late regions (img/xsp dead)
#define H2_OFF 0             // 12 x 30 x 30 bf16  [0,10800)
#define H3_OFF 10800         // 12 x 16 x 16 bf16  [10800,13872)  (< X0H end, dead)
// float-view offsets (h2 dead by then)
#define H4_F 0               // 588 f32 (12x7x7 flatten)
#define FC1_F 600            // 48 f32
#define LG_F 652             // 4 f32

__device__ __forceinline__ unsigned short bfbits(float v) {
  union { __bf16 b; unsigned short u; } c;
  c.b = (__bf16)v;
  return c.u;
}
__device__ __forceinline__ float f_lo(unsigned u) {
  return __uint_as_float(u << 16);
}
__device__ __forceinline__ float f_hi(unsigned u) {
  return __uint_as_float(u & 0xffff0000u);
}

// A-fragments (plain bf16) in MFMA order:
// Aarr[(ft*nks+ks)*64+lane] lanes hold A[l&15][8*(l>>4)+e] of the 16x32 tile.
__global__ void prep_A(const float* __restrict__ ww, int K, int nks,
                       bh8* __restrict__ Aarr) {
  int idx = blockIdx.x * 256 + threadIdx.x;
  int total = 7 * nks * 64;
  if (idx >= total) return;
  int lane = idx & 63;
  int fk = idx >> 6;
  int ks = fk % nks, ft = fk / nks;
  int frow = ft * 16 + (lane & 15);
  int k0 = ks * 32 + 8 * (lane >> 4);
  union { bh8 s; unsigned short h[8]; } o;
  #pragma unroll
  for (int e = 0; e < 8; ++e) {
    int k = k0 + e;
    float v = (k < K) ? ww[(size_t)frow * K + k] : 0.f;
    o.h[e] = bfbits(v);
  }
  Aarr[idx] = o.s;
}

// Per-f-tile nonzero ks-range: bnd[2t]=ks_lo, bnd[2t+1]=ks_hi (exclusive).
__global__ void prep_bounds(const float* __restrict__ ww, int K, int nks,
                            int* __restrict__ bnd) {
  __shared__ int slo[256], shi[256];
  int ft = blockIdx.x, t = threadIdx.x;
  int lo = K, hi = -1;
  for (int m = t; m < 16 * K; m += 256) {
    int f = ft * 16 + m / K, k = m % K;
    if (ww[(size_t)f * K + k] != 0.f) { lo = min(lo, k); hi = max(hi, k); }
  }
  slo[t] = lo; shi[t] = hi;
  __syncthreads();
  for (int s = 128; s > 0; s >>= 1) {
    if (t < s) {
      slo[t] = min(slo[t], slo[t + s]);
      shi[t] = max(shi[t], shi[t + s]);
    }
    __syncthreads();
  }
  if (t == 0) {
    int l = slo[0], h = shi[0];
    if (h < 0) { bnd[2 * ft] = 0; bnd[2 * ft + 1] = 0; }
    else {
      bnd[2 * ft] = l >> 5;
      bnd[2 * ft + 1] = min((h >> 5) + 1, nks);
    }
  }
}

__device__ __forceinline__ void conv4acc(const float (&p)[4][4],
                                         const float (&w9)[9],
                                         float (&acc)[4]) {
  #pragma unroll
  for (int dy = 0; dy < 2; ++dy)
    #pragma unroll
    for (int dx = 0; dx < 2; ++dx) {
      float a = 0.f;
      #pragma unroll
      for (int dr = 0; dr < 3; ++dr)
        #pragma unroll
        for (int dc = 0; dc < 3; ++dc)
          a = fmaf(p[dy + dr][dx + dc], w9[dr * 3 + dc], a);
      acc[dy * 2 + dx] += a;
    }
}

__device__ __forceinline__ void load_patch(const unsigned short* su, int baseEl,
                                           int ldEl, float (&p)[4][4]) {
  #pragma unroll
  for (int i = 0; i < 4; ++i) {
    unsigned a = *(const unsigned*)(su + baseEl + i * ldEl);
    unsigned b = *(const unsigned*)(su + baseEl + i * ldEl + 2);
    p[i][0] = f_lo(a); p[i][1] = f_hi(a);
    p[i][2] = f_lo(b); p[i][3] = f_hi(b);
  }
}

template <bool PRE>
__global__ __launch_bounds__(NTH, 8) void fused_convnet(
    const float* __restrict__ x, const float* __restrict__ ww,
    const bh8* __restrict__ Aarr, const int* __restrict__ bnd,
    int K, int nks,
    const float* __restrict__ c1w, const float* __restrict__ c1b,
    const float* __restrict__ c2w, const float* __restrict__ c2b,
    const float* __restrict__ c3w, const float* __restrict__ c3b,
    const float* __restrict__ c4w, const float* __restrict__ c4b,
    const float* __restrict__ f1w, const float* __restrict__ f1b,
    const float* __restrict__ f2w, const float* __restrict__ f2b,
    float* __restrict__ out) {
  extern __shared__ unsigned short su[];
  float* sfl = (float*)su;
  const int b = blockIdx.x;
  const int tid = threadIdx.x;
  const int pad = (K - 1) >> 1;

  // ---- phase 0: halo rings + stage xsp bf16 (dual parity) ----
  for (int m = tid; m < 452; m += NTH) {  // img ring
    int r, c;
    if (m < 114) { r = 0; c = m; }
    else if (m < 228) { r = 113; c = m - 114; }
    else if (m < 340) { r = m - 228 + 1; c = 0; }
    else { r = m - 340 + 1; c = 113; }
    su[IMG_OFF + r * IMG_LD + c] = 0;
  }
  for (int m = tid; m < 1368; m += NTH) {  // h1 rings
    int ch = m / 228, w = m - ch * 228, r, c;
    if (w < 58) { r = 0; c = w; }
    else if (w < 116) { r = 57; c = w - 58; }
    else if (w < 172) { r = w - 116 + 1; c = 0; }
    else { r = w - 172 + 1; c = 57; }
    su[H1_OFF + ch * 3364 + r * 58 + c] = 0;
  }
  for (int i = tid; i < 1024; i += NTH) {
    float f0 = 0.f, f1 = 0.f;
    int xi = i - pad;
    if (xi >= 0 && xi < XLEN) f0 = x[(size_t)b * XLEN + xi];
    if (xi + 1 >= 0 && xi + 1 < XLEN) f1 = x[(size_t)b * XLEN + xi + 1];
    su[X0H + i] = bfbits(f0);
    su[X1H + i] = bfbits(f1);
  }
  __syncthreads();

  // ---- phase 1: CWT via MFMA, per-f-tile ks bounds, 1 acc/pass ----
  {
    const int wid = __builtin_amdgcn_readfirstlane(tid >> 6);
    const int lane = tid & 63;
    const int koff = (lane >> 4) * 8;
    #pragma unroll 1
    for (int tile = wid; tile < 49; tile += 16) {
      const int ft = tile / 7, jt = tile - ft * 7;
      int klo = 0, khi = nks;
      if (PRE) { klo = bnd[2 * ft]; khi = bnd[2 * ft + 1]; }
      const int jcol = jt * 16 + (lane & 15);
      const int selj = (jcol == NF - 1)
          ? (XLEN - 1)
          : (int)((double)jcol * ((double)(XLEN - 1) / (double)(NF - 1)));
      fv4 acc = {0.f, 0.f, 0.f, 0.f};
      for (int ks = klo; ks < khi; ++ks) {
        const int kbase = selj + (ks << 5) + koff;
        const int par = kbase & 1;
        const int e0 = kbase - par;
        const unsigned* ph = (const unsigned*)(su + (par ? X1H : X0H) + e0);
        union { bh8 v; unsigned u[4]; } bh_;
        #pragma unroll
        for (int j = 0; j < 4; ++j) bh_.u[j] = ph[j];
        bh8 ah;
        if (PRE) {
          ah = Aarr[((size_t)ft * nks + ks) * 64 + lane];
        } else {
          const int frow = ft * 16 + (lane & 15);
          union { bh8 s; unsigned short h[8]; } ha;
          #pragma unroll
          for (int e = 0; e < 8; ++e) {
            int k = (ks << 5) + koff + e;
            float v = (k < K) ? ww[(size_t)frow * K + k] : 0.f;
            ha.h[e] = bfbits(v);
          }
          ah = ha.s;
        }
        acc = __builtin_amdgcn_mfma_f32_16x16x32_bf16(ah, bh_.v, acc, 0, 0, 0);
      }
      const int col = jt * 16 + (lane & 15) + 1;
      const int fbase = ft * 16 + (lane >> 4) * 4 + 1;
      #pragma unroll
      for (int r = 0; r < 4; ++r)
        su[IMG_OFF + (fbase + r) * IMG_LD + col] = bfbits(acc[r]);
    }
  }
  __syncthreads();

  // ---- phase 2: conv1(1->6)+relu+pool -> h1 bf16 ----
  for (int it = tid; it < 3136; it += NTH) {
    int pr = it / 56, pc = it - pr * 56;
    float p[4][4];
    load_patch(su, IMG_OFF + (pr * 2) * IMG_LD + pc * 2, IMG_LD, p);
    #pragma unroll
    for (int oc = 0; oc < 6; ++oc) {
      float w9[9];
      #pragma unroll
      for (int t = 0; t < 9; ++t) w9[t] = c1w[oc * 9 + t];
      float acc[4] = {c1b[oc], c1b[oc], c1b[oc], c1b[oc]};
      conv4acc(p, w9, acc);
      float m = fmaxf(fmaxf(acc[0], acc[1]), fmaxf(acc[2], acc[3]));
      su[H1_OFF + oc * 3364 + (pr + 1) * 58 + (pc + 1)] = bfbits(fmaxf(m, 0.f));
    }
  }
  __syncthreads();

  // ---- phase 3: conv2 in 4 oc-triple passes (tid<784) | rings ----
  if (tid < 784) {
    int pr = tid / 28, pc = tid - pr * 28;
    #pragma unroll 1
    for (int ob = 0; ob < 4; ++ob) {
      int oc0 = ob * 3;
      float acc[3][4];
      #pragma unroll
      for (int q = 0; q < 3; ++q) {
        float bia = c2b[oc0 + q];
        #pragma unroll
        for (int t = 0; t < 4; ++t) acc[q][t] = bia;
      }
      for (int ic = 0; ic < 6; ++ic) {
        float p[4][4];
        load_patch(su, H1_OFF + ic * 3364 + (pr * 2) * 58 + pc * 2, 58, p);
        #pragma unroll
        for (int q = 0; q < 3; ++q) {
          const float* wp = c2w + ((size_t)(oc0 + q) * 6 + ic) * 9;
          float w9[9];
          #pragma unroll
          for (int t = 0; t < 9; ++t) w9[t] = wp[t];
          conv4acc(p, w9, acc[q]);
        }
      }
      #pragma unroll
      for (int q = 0; q < 3; ++q) {
        float m = fmaxf(fmaxf(acc[q][0], acc[q][1]),
                        fmaxf(acc[q][2], acc[q][3]));
        su[H2_OFF + (oc0 + q) * 900 + (pr + 1) * 30 + (pc + 1)] =
            bfbits(fmaxf(m, 0.f));
      }
    }
  } else {
    for (int m = tid - 784; m < 1392; m += 240) {  // h2 rings
      int ch = m / 116, w = m - ch * 116, r, c;
      if (w < 30) { r = 0; c = w; }
      else if (w < 60) { r = 29; c = w - 30; }
      else if (w < 88) { r = w - 60 + 1; c = 0; }
      else { r = w - 88 + 1; c = 29; }
      su[H2_OFF + ch * 900 + r * 30 + c] = 0;
    }
    for (int m = tid - 784; m < 720; m += 240) {  // h3 rings
      int ch = m / 60, w = m - ch * 60, r, c;
      if (w < 16) { r = 0; c = w; }
      else if (w < 32) { r = 15; c = w - 16; }
      else if (w < 46) { r = w - 32 + 1; c = 0; }
      else { r = w - 46 + 1; c = 15; }
      su[H3_OFF + ch * 256 + r * 16 + c] = 0;
    }
  }
  __syncthreads();

  // ---- phase 4: conv3(12->12)+relu+pool quads -> h3 bf16 ----
  if (tid < 784) {
    int pos = tid >> 2, ocq = tid & 3;
    int pr = pos / 14, pc = pos - pr * 14;
    int oc0 = ocq * 3;
    float acc[3][4];
    #pragma unroll
    for (int q = 0; q < 3; ++q) {
      float bia = c3b[oc0 + q];
      #pragma unroll
      for (int t = 0; t < 4; ++t) acc[q][t] = bia;
    }
    for (int ic = 0; ic < 12; ++ic) {
      float p[4][4];
      load_patch(su, H2_OFF + ic * 900 + (pr * 2) * 30 + pc * 2, 30, p);
      #pragma unroll
      for (int q = 0; q < 3; ++q) {
        const float* wp = c3w + ((size_t)(oc0 + q) * 12 + ic) * 9;
        float w9[9];
        #pragma unroll
        for (int t = 0; t < 9; ++t) w9[t] = wp[t];
        conv4acc(p, w9, acc[q]);
      }
    }
    #pragma unroll
    for (int q = 0; q < 3; ++q) {
      float m = fmaxf(fmaxf(acc[q][0], acc[q][1]), fmaxf(acc[q][2], acc[q][3]));
      su[H3_OFF + (oc0 + q) * 256 + (pr + 1) * 16 + (pc + 1)] =
          bfbits(fmaxf(m, 0.f));
    }
  }
  __syncthreads();

  // ---- phase 5: conv4(12->12)+relu+pool quads -> h4 f32 flat ----
  if (tid < 196) {
    int pos = tid >> 2, ocq = tid & 3;
    int pr = pos / 7, pc = pos - pr * 7;
    int oc0 = ocq * 3;
    float acc[3][4];
    #pragma unroll
    for (int q = 0; q < 3; ++q) {
      float bia = c4b[oc0 + q];
      #pragma unroll
      for (int t = 0; t < 4; ++t) acc[q][t] = bia;
    }
    for (int ic = 0; ic < 12; ++ic) {
      float p[4][4];
      load_patch(su, H3_OFF + ic * 256 + (pr * 2) * 16 + pc * 2, 16, p);
      #pragma unroll
      for (int q = 0; q < 3; ++q) {
        const float* wp = c4w + ((size_t)(oc0 + q) * 12 + ic) * 9;
        float w9[9];
        #pragma unroll
        for (int t = 0; t < 9; ++t) w9[t] = wp[t];
        conv4acc(p, w9, acc[q]);
      }
    }
    #pragma unroll
    for (int q = 0; q < 3; ++q) {
      float m = fmaxf(fmaxf(acc[q][0], acc[q][1]), fmaxf(acc[q][2], acc[q][3]));
      sfl[H4_F + (oc0 + q) * 49 + pr * 7 + pc] = fmaxf(m, 0.f);
    }
  }
  __syncthreads();

  // ---- phase 6: fc1 (588 -> 48), one wave per output ----
  {
    int wv = tid >> 6, ln = tid & 63;
    for (int o = wv; o < 48; o += 16) {
      float s = 0.f;
      for (int i = ln; i < 588; i += 64)
        s += sfl[H4_F + i] * f1w[(size_t)o * 588 + i];
      #pragma unroll
      for (int off = 32; off > 0; off >>= 1) s += __shfl_down(s, off);
      if (ln == 0) sfl[FC1_F + o] = fmaxf(s + f1b[o], 0.f);
    }
  }
  __syncthreads();

  // ---- phase 7: fc2 (48 -> 4) + softmax ----
  if (tid < 4) {
    float s = f2b[tid];
    for (int i = 0; i < 48; ++i) s += sfl[FC1_F + i] * f2w[tid * 48 + i];
    sfl[LG_F + tid] = s;
  }
  __syncthreads();
  if (tid < 4) {
    float l0 = sfl[LG_F + 0], l1 = sfl[LG_F + 1];
    float l2 = sfl[LG_F + 2], l3 = sfl[LG_F + 3];
    float m = fmaxf(fmaxf(l0, l1), fmaxf(l2, l3));
    float e0 = expf(l0 - m), e1 = expf(l1 - m);
    float e2 = expf(l2 - m), e3 = expf(l3 - m);
    float ssum = e0 + e1 + e2 + e3;
    out[(size_t)b * 4 + tid] = expf(sfl[LG_F + tid] - m) / ssum;
  }
}

extern "C" void kernel_launch(void* const* d_in, const int* in_sizes, int n_in,
                              void* d_out, int out_size, void* d_ws,
                              size_t ws_size, hipStream_t stream) {
  const float* x   = (const float*)d_in[0];
  const float* ww  = (const float*)d_in[1];
  const float* c1w = (const float*)d_in[2];
  const float* c1b = (const float*)d_in[3];
  const float* c2w = (const float*)d_in[4];
  const float* c2b = (const float*)d_in[5];
  const float* c3w = (const float*)d_in[6];
  const float* c3b = (const float*)d_in[7];
  const float* c4w = (const float*)d_in[8];
  const float* c4b = (const float*)d_in[9];
  const float* f1w = (const float*)d_in[10];
  const float* f1b = (const float*)d_in[11];
  const float* f2w = (const float*)d_in[12];
  const float* f2b = (const float*)d_in[13];
  float* out = (float*)d_out;

  const int B = in_sizes[0] / XLEN;
  const int K = in_sizes[1] / NF;  // 561
  const int nks = (K + 31) / 32;   // 18

  const int items = 7 * nks * 64;
  const size_t aoff = (size_t)items * sizeof(bh8);       // 129024 B
  const size_t abytes = aoff + 16 * sizeof(int);
  const bool pre = ws_size >= abytes;
  bh8* Aarr = (bh8*)d_ws;
  int* bnd = (int*)((char*)d_ws + aoff);

  const size_t smem = (size_t)TOT_E * sizeof(unsigned short);  // 70456 B

  if (pre) {
    hipLaunchKernelGGL(prep_A, dim3((items + 255) / 256), dim3(256), 0, stream,
                       ww, K, nks, Aarr);
    hipLaunchKernelGGL(prep_bounds, dim3(7), dim3(256), 0, stream,
                       ww, K, nks, bnd);
    hipFuncSetAttribute((const void*)fused_convnet<true>,
                        hipFuncAttributeMaxDynamicSharedMemorySize, (int)smem);
    hipLaunchKernelGGL(fused_convnet<true>, dim3(B), dim3(NTH), smem, stream,
                       x, ww, Aarr, bnd, K, nks, c1w, c1b, c2w, c2b, c3w, c3b,
                       c4w, c4b, f1w, f1b, f2w, f2b, out);
  } else {
    hipFuncSetAttribute((const void*)fused_convnet<false>,
                        hipFuncAttributeMaxDynamicSharedMemorySize, (int)smem);
    hipLaunchKernelGGL(fused_convnet<false>, dim3(B), dim3(NTH), smem, stream,
                       x, ww, Aarr, bnd, K, nks, c1w, c1b, c2w, c2b, c3w, c3b,
                       c4w, c4b, f1w, f1b, f2w, f2b, out);
  }
}

// Round 6
// 1435.489 us; speedup vs baseline: 1.6317x; 1.6317x over previous
//
#include <hip/hip_runtime.h>

#define NTH  1024
#define XLEN 368
#define NF   112

typedef short bh8 __attribute__((ext_vector_type(8)));
typedef float fv4 __attribute__((ext_vector_type(4)));

// ---- LDS layout (ushort-element offsets) ----
#define IMG_OFF 0            // 114x114 bf16 zero-halo img   [0,12996)
#define IMG_LD  114
#define X0H 12996            // xsp bf16, even-pair copy     (1024 el)
#define X1H 14020            // xsp bf16, shifted-by-1       (1024 el)
#define H1_OFF 15044         // 6 x 58 x 58 bf16 zero-halo   (20184 el)
#define TOT_E 35228          // *2 = 70456 bytes

// time-aliased late regions (img/xsp dead)
#define H2_OFF 0             // 12 x 30 x 30 bf16  [0,10800)
#define H3_OFF 10800         // 12 x 16 x 16 bf16  [10800,13872)
// float-view offsets (h2 dead by then)
#define H4_F 0               // 588 f32 (12x7x7 flatten)
#define FC1_F 600            // 48 f32
#define LG_F 652             // 4 f32

__device__ __forceinline__ unsigned short bfbits(float v) {
  union { __bf16 b; unsigned short u; } c;
  c.b = (__bf16)v;
  return c.u;
}
__device__ __forceinline__ float f_lo(unsigned u) {
  return __uint_as_float(u << 16);
}
__device__ __forceinline__ float f_hi(unsigned u) {
  return __uint_as_float(u & 0xffff0000u);
}

// A-fragments (plain bf16) in MFMA order:
// Aarr[(ft*nks+ks)*64+lane] lanes hold A[l&15][8*(l>>4)+e] of the 16x32 tile.
__global__ void prep_A(const float* __restrict__ ww, int K, int nks,
                       bh8* __restrict__ Aarr) {
  int idx = blockIdx.x * 256 + threadIdx.x;
  int total = 7 * nks * 64;
  if (idx >= total) return;
  int lane = idx & 63;
  int fk = idx >> 6;
  int ks = fk % nks, ft = fk / nks;
  int frow = ft * 16 + (lane & 15);
  int k0 = ks * 32 + 8 * (lane >> 4);
  union { bh8 s; unsigned short h[8]; } o;
  #pragma unroll
  for (int e = 0; e < 8; ++e) {
    int k = k0 + e;
    float v = (k < K) ? ww[(size_t)frow * K + k] : 0.f;
    o.h[e] = bfbits(v);
  }
  Aarr[idx] = o.s;
}

// Per-f-tile nonzero ks-range: bnd[2t]=ks_lo, bnd[2t+1]=ks_hi (exclusive).
__global__ void prep_bounds(const float* __restrict__ ww, int K, int nks,
                            int* __restrict__ bnd) {
  __shared__ int slo[256], shi[256];
  int ft = blockIdx.x, t = threadIdx.x;
  int lo = K, hi = -1;
  for (int m = t; m < 16 * K; m += 256) {
    int f = ft * 16 + m / K, k = m % K;
    if (ww[(size_t)f * K + k] != 0.f) { lo = min(lo, k); hi = max(hi, k); }
  }
  slo[t] = lo; shi[t] = hi;
  __syncthreads();
  for (int s = 128; s > 0; s >>= 1) {
    if (t < s) {
      slo[t] = min(slo[t], slo[t + s]);
      shi[t] = max(shi[t], shi[t + s]);
    }
    __syncthreads();
  }
  if (t == 0) {
    int l = slo[0], h = shi[0];
    if (h < 0) { bnd[2 * ft] = 0; bnd[2 * ft + 1] = 0; }
    else {
      bnd[2 * ft] = l >> 5;
      bnd[2 * ft + 1] = min((h >> 5) + 1, nks);
    }
  }
}

__device__ __forceinline__ void conv4acc(const float (&p)[4][4],
                                         const float (&w9)[9],
                                         float (&acc)[4]) {
  #pragma unroll
  for (int dy = 0; dy < 2; ++dy)
    #pragma unroll
    for (int dx = 0; dx < 2; ++dx) {
      float a = 0.f;
      #pragma unroll
      for (int dr = 0; dr < 3; ++dr)
        #pragma unroll
        for (int dc = 0; dc < 3; ++dc)
          a = fmaf(p[dy + dr][dx + dc], w9[dr * 3 + dc], a);
      acc[dy * 2 + dx] += a;
    }
}

__device__ __forceinline__ void load_patch(const unsigned short* su, int baseEl,
                                           int ldEl, float (&p)[4][4]) {
  #pragma unroll
  for (int i = 0; i < 4; ++i) {
    unsigned a = *(const unsigned*)(su + baseEl + i * ldEl);
    unsigned b = *(const unsigned*)(su + baseEl + i * ldEl + 2);
    p[i][0] = f_lo(a); p[i][1] = f_hi(a);
    p[i][2] = f_lo(b); p[i][3] = f_hi(b);
  }
}

template <bool PRE>
__global__ __launch_bounds__(NTH) void fused_convnet(
    const float* __restrict__ x, const float* __restrict__ ww,
    const bh8* __restrict__ Aarr, const int* __restrict__ bnd,
    int K, int nks,
    const float* __restrict__ c1w, const float* __restrict__ c1b,
    const float* __restrict__ c2w, const float* __restrict__ c2b,
    const float* __restrict__ c3w, const float* __restrict__ c3b,
    const float* __restrict__ c4w, const float* __restrict__ c4b,
    const float* __restrict__ f1w, const float* __restrict__ f1b,
    const float* __restrict__ f2w, const float* __restrict__ f2b,
    float* __restrict__ out) {
  extern __shared__ unsigned short su[];
  float* sfl = (float*)su;
  const int b = blockIdx.x;
  const int tid = threadIdx.x;
  const int pad = (K - 1) >> 1;

  // ---- phase 0: halo rings + stage xsp bf16 (dual parity) ----
  for (int m = tid; m < 452; m += NTH) {  // img ring
    int r, c;
    if (m < 114) { r = 0; c = m; }
    else if (m < 228) { r = 113; c = m - 114; }
    else if (m < 340) { r = m - 228 + 1; c = 0; }
    else { r = m - 340 + 1; c = 113; }
    su[IMG_OFF + r * IMG_LD + c] = 0;
  }
  for (int m = tid; m < 1368; m += NTH) {  // h1 rings
    int ch = m / 228, w = m - ch * 228, r, c;
    if (w < 58) { r = 0; c = w; }
    else if (w < 116) { r = 57; c = w - 58; }
    else if (w < 172) { r = w - 116 + 1; c = 0; }
    else { r = w - 172 + 1; c = 57; }
    su[H1_OFF + ch * 3364 + r * 58 + c] = 0;
  }
  for (int i = tid; i < 1024; i += NTH) {
    float f0 = 0.f, f1 = 0.f;
    int xi = i - pad;
    if (xi >= 0 && xi < XLEN) f0 = x[(size_t)b * XLEN + xi];
    if (xi + 1 >= 0 && xi + 1 < XLEN) f1 = x[(size_t)b * XLEN + xi + 1];
    su[X0H + i] = bfbits(f0);
    su[X1H + i] = bfbits(f1);
  }
  __syncthreads();

  // ---- phase 1: CWT via MFMA, per-f-tile ks bounds, 1 acc/pass ----
  {
    const int wid = __builtin_amdgcn_readfirstlane(tid >> 6);
    const int lane = tid & 63;
    const int koff = (lane >> 4) * 8;
    #pragma unroll 1
    for (int tile = wid; tile < 49; tile += 16) {
      const int ft = tile / 7, jt = tile - ft * 7;
      int klo = 0, khi = nks;
      if (PRE) { klo = bnd[2 * ft]; khi = bnd[2 * ft + 1]; }
      const int jcol = jt * 16 + (lane & 15);
      const int selj = (jcol == NF - 1)
          ? (XLEN - 1)
          : (int)((double)jcol * ((double)(XLEN - 1) / (double)(NF - 1)));
      fv4 acc = {0.f, 0.f, 0.f, 0.f};
      for (int ks = klo; ks < khi; ++ks) {
        const int kbase = selj + (ks << 5) + koff;
        const int par = kbase & 1;
        const int e0 = kbase - par;
        const unsigned* ph = (const unsigned*)(su + (par ? X1H : X0H) + e0);
        union { bh8 v; unsigned u[4]; } bh_;
        #pragma unroll
        for (int j = 0; j < 4; ++j) bh_.u[j] = ph[j];
        bh8 ah;
        if (PRE) {
          ah = Aarr[((size_t)ft * nks + ks) * 64 + lane];
        } else {
          const int frow = ft * 16 + (lane & 15);
          union { bh8 s; unsigned short h[8]; } ha;
          #pragma unroll
          for (int e = 0; e < 8; ++e) {
            int k = (ks << 5) + koff + e;
            float v = (k < K) ? ww[(size_t)frow * K + k] : 0.f;
            ha.h[e] = bfbits(v);
          }
          ah = ha.s;
        }
        acc = __builtin_amdgcn_mfma_f32_16x16x32_bf16(ah, bh_.v, acc, 0, 0, 0);
      }
      const int col = jt * 16 + (lane & 15) + 1;
      const int fbase = ft * 16 + (lane >> 4) * 4 + 1;
      #pragma unroll
      for (int r = 0; r < 4; ++r)
        su[IMG_OFF + (fbase + r) * IMG_LD + col] = bfbits(acc[r]);
    }
  }
  __syncthreads();

  // ---- phase 2: conv1(1->6)+relu+pool -> h1 bf16 ----
  for (int it = tid; it < 3136; it += NTH) {
    int pr = it / 56, pc = it - pr * 56;
    float p[4][4];
    load_patch(su, IMG_OFF + (pr * 2) * IMG_LD + pc * 2, IMG_LD, p);
    #pragma unroll
    for (int oc = 0; oc < 6; ++oc) {
      float w9[9];
      #pragma unroll
      for (int t = 0; t < 9; ++t) w9[t] = c1w[oc * 9 + t];
      float acc[4] = {c1b[oc], c1b[oc], c1b[oc], c1b[oc]};
      conv4acc(p, w9, acc);
      float m = fmaxf(fmaxf(acc[0], acc[1]), fmaxf(acc[2], acc[3]));
      su[H1_OFF + oc * 3364 + (pr + 1) * 58 + (pc + 1)] = bfbits(fmaxf(m, 0.f));
    }
  }
  __syncthreads();

  // ---- phase 3: conv2 in 4 oc-triple passes (tid<784) | rings ----
  if (tid < 784) {
    int pr = tid / 28, pc = tid - pr * 28;
    #pragma unroll 1
    for (int ob = 0; ob < 4; ++ob) {
      int oc0 = ob * 3;
      float acc[3][4];
      #pragma unroll
      for (int q = 0; q < 3; ++q) {
        float bia = c2b[oc0 + q];
        #pragma unroll
        for (int t = 0; t < 4; ++t) acc[q][t] = bia;
      }
      for (int ic = 0; ic < 6; ++ic) {
        float p[4][4];
        load_patch(su, H1_OFF + ic * 3364 + (pr * 2) * 58 + pc * 2, 58, p);
        #pragma unroll
        for (int q = 0; q < 3; ++q) {
          const float* wp = c2w + ((size_t)(oc0 + q) * 6 + ic) * 9;
          float w9[9];
          #pragma unroll
          for (int t = 0; t < 9; ++t) w9[t] = wp[t];
          conv4acc(p, w9, acc[q]);
        }
      }
      #pragma unroll
      for (int q = 0; q < 3; ++q) {
        float m = fmaxf(fmaxf(acc[q][0], acc[q][1]),
                        fmaxf(acc[q][2], acc[q][3]));
        su[H2_OFF + (oc0 + q) * 900 + (pr + 1) * 30 + (pc + 1)] =
            bfbits(fmaxf(m, 0.f));
      }
    }
  } else {
    for (int m = tid - 784; m < 1392; m += 240) {  // h2 rings
      int ch = m / 116, w = m - ch * 116, r, c;
      if (w < 30) { r = 0; c = w; }
      else if (w < 60) { r = 29; c = w - 30; }
      else if (w < 88) { r = w - 60 + 1; c = 0; }
      else { r = w - 88 + 1; c = 29; }
      su[H2_OFF + ch * 900 + r * 30 + c] = 0;
    }
    for (int m = tid - 784; m < 720; m += 240) {  // h3 rings
      int ch = m / 60, w = m - ch * 60, r, c;
      if (w < 16) { r = 0; c = w; }
      else if (w < 32) { r = 15; c = w - 16; }
      else if (w < 46) { r = w - 32 + 1; c = 0; }
      else { r = w - 46 + 1; c = 15; }
      su[H3_OFF + ch * 256 + r * 16 + c] = 0;
    }
  }
  __syncthreads();

  // ---- phase 4: conv3(12->12)+relu+pool quads -> h3 bf16 ----
  if (tid < 784) {
    int pos = tid >> 2, ocq = tid & 3;
    int pr = pos / 14, pc = pos - pr * 14;
    int oc0 = ocq * 3;
    float acc[3][4];
    #pragma unroll
    for (int q = 0; q < 3; ++q) {
      float bia = c3b[oc0 + q];
      #pragma unroll
      for (int t = 0; t < 4; ++t) acc[q][t] = bia;
    }
    for (int ic = 0; ic < 12; ++ic) {
      float p[4][4];
      load_patch(su, H2_OFF + ic * 900 + (pr * 2) * 30 + pc * 2, 30, p);
      #pragma unroll
      for (int q = 0; q < 3; ++q) {
        const float* wp = c3w + ((size_t)(oc0 + q) * 12 + ic) * 9;
        float w9[9];
        #pragma unroll
        for (int t = 0; t < 9; ++t) w9[t] = wp[t];
        conv4acc(p, w9, acc[q]);
      }
    }
    #pragma unroll
    for (int q = 0; q < 3; ++q) {
      float m = fmaxf(fmaxf(acc[q][0], acc[q][1]), fmaxf(acc[q][2], acc[q][3]));
      su[H3_OFF + (oc0 + q) * 256 + (pr + 1) * 16 + (pc + 1)] =
          bfbits(fmaxf(m, 0.f));
    }
  }
  __syncthreads();

  // ---- phase 5: conv4(12->12)+relu+pool quads -> h4 f32 flat ----
  if (tid < 196) {
    int pos = tid >> 2, ocq = tid & 3;
    int pr = pos / 7, pc = pos - pr * 7;
    int oc0 = ocq * 3;
    float acc[3][4];
    #pragma unroll
    for (int q = 0; q < 3; ++q) {
      float bia = c4b[oc0 + q];
      #pragma unroll
      for (int t = 0; t < 4; ++t) acc[q][t] = bia;
    }
    for (int ic = 0; ic < 12; ++ic) {
      float p[4][4];
      load_patch(su, H3_OFF + ic * 256 + (pr * 2) * 16 + pc * 2, 16, p);
      #pragma unroll
      for (int q = 0; q < 3; ++q) {
        const float* wp = c4w + ((size_t)(oc0 + q) * 12 + ic) * 9;
        float w9[9];
        #pragma unroll
        for (int t = 0; t < 9; ++t) w9[t] = wp[t];
        conv4acc(p, w9, acc[q]);
      }
    }
    #pragma unroll
    for (int q = 0; q < 3; ++q) {
      float m = fmaxf(fmaxf(acc[q][0], acc[q][1]), fmaxf(acc[q][2], acc[q][3]));
      sfl[H4_F + (oc0 + q) * 49 + pr * 7 + pc] = fmaxf(m, 0.f);
    }
  }
  __syncthreads();

  // ---- phase 6: fc1 (588 -> 48), one wave per output ----
  {
    int wv = tid >> 6, ln = tid & 63;
    for (int o = wv; o < 48; o += 16) {
      float s = 0.f;
      for (int i = ln; i < 588; i += 64)
        s += sfl[H4_F + i] * f1w[(size_t)o * 588 + i];
      #pragma unroll
      for (int off = 32; off > 0; off >>= 1) s += __shfl_down(s, off);
      if (ln == 0) sfl[FC1_F + o] = fmaxf(s + f1b[o], 0.f);
    }
  }
  __syncthreads();

  // ---- phase 7: fc2 (48 -> 4) + softmax ----
  if (tid < 4) {
    float s = f2b[tid];
    for (int i = 0; i < 48; ++i) s += sfl[FC1_F + i] * f2w[tid * 48 + i];
    sfl[LG_F + tid] = s;
  }
  __syncthreads();
  if (tid < 4) {
    float l0 = sfl[LG_F + 0], l1 = sfl[LG_F + 1];
    float l2 = sfl[LG_F + 2], l3 = sfl[LG_F + 3];
    float m = fmaxf(fmaxf(l0, l1), fmaxf(l2, l3));
    float e0 = expf(l0 - m), e1 = expf(l1 - m);
    float e2 = expf(l2 - m), e3 = expf(l3 - m);
    float ssum = e0 + e1 + e2 + e3;
    out[(size_t)b * 4 + tid] = expf(sfl[LG_F + tid] - m) / ssum;
  }
}

extern "C" void kernel_launch(void* const* d_in, const int* in_sizes, int n_in,
                              void* d_out, int out_size, void* d_ws,
                              size_t ws_size, hipStream_t stream) {
  const float* x   = (const float*)d_in[0];
  const float* ww  = (const float*)d_in[1];
  const float* c1w = (const float*)d_in[2];
  const float* c1b = (const float*)d_in[3];
  const float* c2w = (const float*)d_in[4];
  const float* c2b = (const float*)d_in[5];
  const float* c3w = (const float*)d_in[6];
  const float* c3b = (const float*)d_in[7];
  const float* c4w = (const float*)d_in[8];
  const float* c4b = (const float*)d_in[9];
  const float* f1w = (const float*)d_in[10];
  const float* f1b = (const float*)d_in[11];
  const float* f2w = (const float*)d_in[12];
  const float* f2b = (const float*)d_in[13];
  float* out = (float*)d_out;

  const int B = in_sizes[0] / XLEN;
  const int K = in_sizes[1] / NF;  // 561
  const int nks = (K + 31) / 32;   // 18

  const int items = 7 * nks * 64;
  const size_t aoff = (size_t)items * sizeof(bh8);       // 129024 B
  const size_t abytes = aoff + 16 * sizeof(int);
  const bool pre = ws_size >= abytes;
  bh8* Aarr = (bh8*)d_ws;
  int* bnd = (int*)((char*)d_ws + aoff);

  const size_t smem = (size_t)TOT_E * sizeof(unsigned short);  // 70456 B

  if (pre) {
    hipLaunchKernelGGL(prep_A, dim3((items + 255) / 256), dim3(256), 0, stream,
                       ww, K, nks, Aarr);
    hipLaunchKernelGGL(prep_bounds, dim3(7), dim3(256), 0, stream,
                       ww, K, nks, bnd);
    hipFuncSetAttribute((const void*)fused_convnet<true>,
                        hipFuncAttributeMaxDynamicSharedMemorySize, (int)smem);
    hipLaunchKernelGGL(fused_convnet<true>, dim3(B), dim3(NTH), smem, stream,
                       x, ww, Aarr, bnd, K, nks, c1w, c1b, c2w, c2b, c3w, c3b,
                       c4w, c4b, f1w, f1b, f2w, f2b, out);
  } else {
    hipFuncSetAttribute((const void*)fused_convnet<false>,
                        hipFuncAttributeMaxDynamicSharedMemorySize, (int)smem);
    hipLaunchKernelGGL(fused_convnet<false>, dim3(B), dim3(NTH), smem, stream,
                       x, ww, Aarr, bnd, K, nks, c1w, c1b, c2w, c2b, c3w, c3b,
                       c4w, c4b, f1w, f1b, f2w, f2b, out);
  }
}

// Round 7
// 384.790 us; speedup vs baseline: 6.0873x; 3.7306x over previous
//
#include <hip/hip_runtime.h>

#define NTH  512
#define XLEN 368
#define NF   112

typedef short bh8 __attribute__((ext_vector_type(8)));
typedef float fv4 __attribute__((ext_vector_type(4)));

// ---- LDS layout (ushort-element offsets) ----
#define IMG_OFF 0            // 114x114 bf16 zero-halo img   [0,12996)
#define IMG_LD  114
#define X0H 12996            // xsp bf16, even-pair copy     (1024 el)
#define X1H 14020            // xsp bf16, shifted-by-1       (1024 el)
#define H1_OFF 15044         // 6 x 58 x 58 bf16 zero-halo   (20184 el)
#define TOT_E 35228          // *2 = 70456 bytes -> 2 blocks/CU

// time-aliased late regions (img/xsp dead after conv1)
#define H2_OFF 0             // 12 x 30 x 30 bf16  [0,10800)
#define H3_OFF 10800         // 12 x 16 x 16 bf16  [10800,13872)
// float-view offsets (h2 dead during conv4/fc)
#define H4_F 0               // 588 f32 (12x7x7 flatten)
#define FC1_F 600            // 48 f32
#define LG_F 652             // 4 f32

__device__ __forceinline__ unsigned short bfbits(float v) {
  union { __bf16 b; unsigned short u; } c;
  c.b = (__bf16)v;
  return c.u;
}
__device__ __forceinline__ float f_lo(unsigned u) {
  return __uint_as_float(u << 16);
}
__device__ __forceinline__ float f_hi(unsigned u) {
  return __uint_as_float(u & 0xffff0000u);
}

// A-fragments (plain bf16) in MFMA order for the CWT.
__global__ void prep_A(const float* __restrict__ ww, int K, int nks,
                       bh8* __restrict__ Aarr) {
  int idx = blockIdx.x * 256 + threadIdx.x;
  int total = 7 * nks * 64;
  if (idx >= total) return;
  int lane = idx & 63;
  int fk = idx >> 6;
  int ks = fk % nks, ft = fk / nks;
  int frow = ft * 16 + (lane & 15);
  int k0 = ks * 32 + 8 * (lane >> 4);
  union { bh8 s; unsigned short h[8]; } o;
  #pragma unroll
  for (int e = 0; e < 8; ++e) {
    int k = k0 + e;
    float v = (k < K) ? ww[(size_t)frow * K + k] : 0.f;
    o.h[e] = bfbits(v);
  }
  Aarr[idx] = o.s;
}

// Per-f-tile nonzero ks-range.
__global__ void prep_bounds(const float* __restrict__ ww, int K, int nks,
                            int* __restrict__ bnd) {
  __shared__ int slo[256], shi[256];
  int ft = blockIdx.x, t = threadIdx.x;
  int lo = K, hi = -1;
  for (int m = t; m < 16 * K; m += 256) {
    int f = ft * 16 + m / K, k = m % K;
    if (ww[(size_t)f * K + k] != 0.f) { lo = min(lo, k); hi = max(hi, k); }
  }
  slo[t] = lo; shi[t] = hi;
  __syncthreads();
  for (int s = 128; s > 0; s >>= 1) {
    if (t < s) {
      slo[t] = min(slo[t], slo[t + s]);
      shi[t] = max(shi[t], shi[t + s]);
    }
    __syncthreads();
  }
  if (t == 0) {
    int l = slo[0], h = shi[0];
    if (h < 0) { bnd[2 * ft] = 0; bnd[2 * ft + 1] = 0; }
    else {
      bnd[2 * ft] = l >> 5;
      bnd[2 * ft + 1] = min((h >> 5) + 1, nks);
    }
  }
}

__device__ __forceinline__ void conv4acc(const float (&p)[4][4],
                                         const float (&w9)[9],
                                         float (&acc)[4]) {
  #pragma unroll
  for (int dy = 0; dy < 2; ++dy)
    #pragma unroll
    for (int dx = 0; dx < 2; ++dx) {
      float a = 0.f;
      #pragma unroll
      for (int dr = 0; dr < 3; ++dr)
        #pragma unroll
        for (int dc = 0; dc < 3; ++dc)
          a = fmaf(p[dy + dr][dx + dc], w9[dr * 3 + dc], a);
      acc[dy * 2 + dx] += a;
    }
}

__device__ __forceinline__ void load_patch(const unsigned short* su, int baseEl,
                                           int ldEl, float (&p)[4][4]) {
  #pragma unroll
  for (int i = 0; i < 4; ++i) {
    unsigned a = *(const unsigned*)(su + baseEl + i * ldEl);
    unsigned b = *(const unsigned*)(su + baseEl + i * ldEl + 2);
    p[i][0] = f_lo(a); p[i][1] = f_hi(a);
    p[i][2] = f_lo(b); p[i][3] = f_hi(b);
  }
}

// Implicit-GEMM conv via MFMA with pooled-quad point ordering.
// A: wgt[oc][k], oc=lane&15, k=ks*32+8*(lane>>4)+e (flat [OC][IC][3][3]).
// B: per-lane gather from halo'd LDS at base(point)+off(k).
// C: row=(lane>>4)*4+r = oc, col=lane&15 = point; 2x2 pool via shfl_xor 1,2.
template <int NKS, int KREAL, int NOC, bool F32OUT>
__device__ __forceinline__ void conv_mfma(
    unsigned short* su, float* sfl, int tid,
    int inOff, int inLD, int inCh,
    int outOff, int outLD, int outCh, int plW,
    int NT, int NPOOL,
    const float* __restrict__ wgt, const float* __restrict__ bias) {
  const int lane = tid & 63;
  const int wid = tid >> 6;
  const int oc_a = lane & 15;
  const int koff = (lane >> 4) * 8;
  const int row0 = (lane >> 4) * 4;

  bh8 afr[NKS];
  int off[NKS][8];
  #pragma unroll
  for (int ks = 0; ks < NKS; ++ks) {
    union { bh8 s; unsigned short h[8]; } au;
    #pragma unroll
    for (int e = 0; e < 8; ++e) {
      int k = ks * 32 + koff + e;
      au.h[e] = (oc_a < NOC && k < KREAL)
                    ? bfbits(wgt[oc_a * KREAL + k]) : (unsigned short)0;
      int kc = (k < KREAL) ? k : 0;
      int ic = kc / 9, rem = kc - ic * 9;
      off[ks][e] = ic * inCh + (rem / 3) * inLD + (rem - (rem / 3) * 3);
    }
    afr[ks] = au.s;
  }
  float biasv[4];
  #pragma unroll
  for (int r = 0; r < 4; ++r)
    biasv[r] = (row0 + r < NOC) ? bias[row0 + r] : 0.f;

  for (int t = wid; t < NT; t += NTH / 64) {
    int n = t * 16 + oc_a;  // col index (lane&15)
    int p = n >> 2, q = n & 3;
    int pp = (p < NPOOL) ? p : 0;
    int pr = pp / plW, pc = pp - pr * plW;
    int r = pr * 2 + (q >> 1), c = pc * 2 + (q & 1);
    int base = inOff + r * inLD + c;
    fv4 acc = {biasv[0], biasv[1], biasv[2], biasv[3]};
    #pragma unroll
    for (int ks = 0; ks < NKS; ++ks) {
      union { bh8 v; unsigned short h[8]; } bu;
      #pragma unroll
      for (int e = 0; e < 8; ++e) bu.h[e] = su[base + off[ks][e]];
      acc = __builtin_amdgcn_mfma_f32_16x16x32_bf16(afr[ks], bu.v, acc, 0, 0, 0);
    }
    #pragma unroll
    for (int r4 = 0; r4 < 4; ++r4) {
      float v = acc[r4];
      v = fmaxf(v, __shfl_xor(v, 1));
      v = fmaxf(v, __shfl_xor(v, 2));
      v = fmaxf(v, 0.f);
      int oc = row0 + r4;
      if ((lane & 3) == 0 && oc < NOC && p < NPOOL) {
        if (F32OUT)
          sfl[outOff + oc * (plW * plW) + pr * plW + pc] = v;
        else
          su[outOff + oc * outCh + (pr + 1) * outLD + (pc + 1)] = bfbits(v);
      }
    }
  }
}

template <bool PRE>
__global__ __launch_bounds__(NTH, 4) void fused_convnet(
    const float* __restrict__ x, const float* __restrict__ ww,
    const bh8* __restrict__ Aarr, const int* __restrict__ bnd,
    int K, int nks,
    const float* __restrict__ c1w, const float* __restrict__ c1b,
    const float* __restrict__ c2w, const float* __restrict__ c2b,
    const float* __restrict__ c3w, const float* __restrict__ c3b,
    const float* __restrict__ c4w, const float* __restrict__ c4b,
    const float* __restrict__ f1w, const float* __restrict__ f1b,
    const float* __restrict__ f2w, const float* __restrict__ f2b,
    float* __restrict__ out) {
  extern __shared__ unsigned short su[];
  float* sfl = (float*)su;
  const int b = blockIdx.x;
  const int tid = threadIdx.x;
  const int pad = (K - 1) >> 1;

  // ---- phase 0: halo rings (img,h1) + stage xsp bf16 (dual parity) ----
  for (int m = tid; m < 452; m += NTH) {
    int r, c;
    if (m < 114) { r = 0; c = m; }
    else if (m < 228) { r = 113; c = m - 114; }
    else if (m < 340) { r = m - 228 + 1; c = 0; }
    else { r = m - 340 + 1; c = 113; }
    su[IMG_OFF + r * IMG_LD + c] = 0;
  }
  for (int m = tid; m < 1368; m += NTH) {
    int ch = m / 228, w = m - ch * 228, r, c;
    if (w < 58) { r = 0; c = w; }
    else if (w < 116) { r = 57; c = w - 58; }
    else if (w < 172) { r = w - 116 + 1; c = 0; }
    else { r = w - 172 + 1; c = 57; }
    su[H1_OFF + ch * 3364 + r * 58 + c] = 0;
  }
  for (int i = tid; i < 1024; i += NTH) {
    float f0 = 0.f, f1 = 0.f;
    int xi = i - pad;
    if (xi >= 0 && xi < XLEN) f0 = x[(size_t)b * XLEN + xi];
    if (xi + 1 >= 0 && xi + 1 < XLEN) f1 = x[(size_t)b * XLEN + xi + 1];
    su[X0H + i] = bfbits(f0);
    su[X1H + i] = bfbits(f1);
  }
  __syncthreads();

  // ---- phase 1: CWT via MFMA (49 tiles / 8 waves) -> img bf16 ----
  {
    const int wid = __builtin_amdgcn_readfirstlane(tid >> 6);
    const int lane = tid & 63;
    const int koff = (lane >> 4) * 8;
    #pragma unroll 1
    for (int tile = wid; tile < 49; tile += NTH / 64) {
      const int ft = tile / 7, jt = tile - ft * 7;
      int klo = 0, khi = nks;
      if (PRE) { klo = bnd[2 * ft]; khi = bnd[2 * ft + 1]; }
      const int jcol = jt * 16 + (lane & 15);
      const int selj = (jcol == NF - 1)
          ? (XLEN - 1)
          : (int)((double)jcol * ((double)(XLEN - 1) / (double)(NF - 1)));
      fv4 acc = {0.f, 0.f, 0.f, 0.f};
      for (int ks = klo; ks < khi; ++ks) {
        const int kbase = selj + (ks << 5) + koff;
        const int par = kbase & 1;
        const int e0 = kbase - par;
        const unsigned* ph = (const unsigned*)(su + (par ? X1H : X0H) + e0);
        union { bh8 v; unsigned u[4]; } bh_;
        #pragma unroll
        for (int j = 0; j < 4; ++j) bh_.u[j] = ph[j];
        bh8 ah;
        if (PRE) {
          ah = Aarr[((size_t)ft * nks + ks) * 64 + lane];
        } else {
          const int frow = ft * 16 + (lane & 15);
          union { bh8 s; unsigned short h[8]; } ha;
          #pragma unroll
          for (int e = 0; e < 8; ++e) {
            int k = (ks << 5) + koff + e;
            float v = (k < K) ? ww[(size_t)frow * K + k] : 0.f;
            ha.h[e] = bfbits(v);
          }
          ah = ha.s;
        }
        acc = __builtin_amdgcn_mfma_f32_16x16x32_bf16(ah, bh_.v, acc, 0, 0, 0);
      }
      const int col = jt * 16 + (lane & 15) + 1;
      const int fbase = ft * 16 + (lane >> 4) * 4 + 1;
      #pragma unroll
      for (int r = 0; r < 4; ++r)
        su[IMG_OFF + (fbase + r) * IMG_LD + col] = bfbits(acc[r]);
    }
  }
  __syncthreads();

  // ---- phase 2: conv1(1->6)+relu+pool scalar -> h1 bf16 ----
  for (int it = tid; it < 3136; it += NTH) {
    int pr = it / 56, pc = it - pr * 56;
    float p[4][4];
    load_patch(su, IMG_OFF + (pr * 2) * IMG_LD + pc * 2, IMG_LD, p);
    #pragma unroll
    for (int oc = 0; oc < 6; ++oc) {
      float w9[9];
      #pragma unroll
      for (int t = 0; t < 9; ++t) w9[t] = c1w[oc * 9 + t];
      float acc[4] = {c1b[oc], c1b[oc], c1b[oc], c1b[oc]};
      conv4acc(p, w9, acc);
      float m = fmaxf(fmaxf(acc[0], acc[1]), fmaxf(acc[2], acc[3]));
      su[H1_OFF + oc * 3364 + (pr + 1) * 58 + (pc + 1)] = bfbits(fmaxf(m, 0.f));
    }
  }
  __syncthreads();

  // ---- phase 3: zero h2/h3 halo rings (img/xsp regions now dead) ----
  for (int m = tid; m < 1392; m += NTH) {
    int ch = m / 116, w = m - ch * 116, r, c;
    if (w < 30) { r = 0; c = w; }
    else if (w < 60) { r = 29; c = w - 30; }
    else if (w < 88) { r = w - 60 + 1; c = 0; }
    else { r = w - 88 + 1; c = 29; }
    su[H2_OFF + ch * 900 + r * 30 + c] = 0;
  }
  for (int m = tid; m < 720; m += NTH) {
    int ch = m / 60, w = m - ch * 60, r, c;
    if (w < 16) { r = 0; c = w; }
    else if (w < 32) { r = 15; c = w - 16; }
    else if (w < 46) { r = w - 32 + 1; c = 0; }
    else { r = w - 46 + 1; c = 15; }
    su[H3_OFF + ch * 256 + r * 16 + c] = 0;
  }
  __syncthreads();

  // ---- phase 4: conv2 (6->12, K=54) MFMA -> h2 bf16 ----
  conv_mfma<2, 54, 12, false>(su, sfl, tid, H1_OFF, 58, 3364,
                              H2_OFF, 30, 900, 28, 196, 784, c2w, c2b);
  __syncthreads();

  // ---- phase 5: conv3 (12->12, K=108) MFMA -> h3 bf16 ----
  conv_mfma<4, 108, 12, false>(su, sfl, tid, H2_OFF, 30, 900,
                               H3_OFF, 16, 256, 14, 49, 196, c3w, c3b);
  __syncthreads();

  // ---- phase 6: conv4 (12->12, K=108) MFMA -> h4 f32 flat ----
  conv_mfma<4, 108, 12, true>(su, sfl, tid, H3_OFF, 16, 256,
                              H4_F, 0, 0, 7, 13, 49, c4w, c4b);
  __syncthreads();

  // ---- phase 7: fc1 (588 -> 48), one wave per output ----
  {
    int wv = tid >> 6, ln = tid & 63;
    for (int o = wv; o < 48; o += NTH / 64) {
      float s = 0.f;
      for (int i = ln; i < 588; i += 64)
        s += sfl[H4_F + i] * f1w[(size_t)o * 588 + i];
      #pragma unroll
      for (int off = 32; off > 0; off >>= 1) s += __shfl_down(s, off);
      if (ln == 0) sfl[FC1_F + o] = fmaxf(s + f1b[o], 0.f);
    }
  }
  __syncthreads();

  // ---- phase 8: fc2 (48 -> 4) + softmax ----
  if (tid < 4) {
    float s = f2b[tid];
    for (int i = 0; i < 48; ++i) s += sfl[FC1_F + i] * f2w[tid * 48 + i];
    sfl[LG_F + tid] = s;
  }
  __syncthreads();
  if (tid < 4) {
    float l0 = sfl[LG_F + 0], l1 = sfl[LG_F + 1];
    float l2 = sfl[LG_F + 2], l3 = sfl[LG_F + 3];
    float m = fmaxf(fmaxf(l0, l1), fmaxf(l2, l3));
    float e0 = expf(l0 - m), e1 = expf(l1 - m);
    float e2 = expf(l2 - m), e3 = expf(l3 - m);
    float ssum = e0 + e1 + e2 + e3;
    out[(size_t)b * 4 + tid] = expf(sfl[LG_F + tid] - m) / ssum;
  }
}

extern "C" void kernel_launch(void* const* d_in, const int* in_sizes, int n_in,
                              void* d_out, int out_size, void* d_ws,
                              size_t ws_size, hipStream_t stream) {
  const float* x   = (const float*)d_in[0];
  const float* ww  = (const float*)d_in[1];
  const float* c1w = (const float*)d_in[2];
  const float* c1b = (const float*)d_in[3];
  const float* c2w = (const float*)d_in[4];
  const float* c2b = (const float*)d_in[5];
  const float* c3w = (const float*)d_in[6];
  const float* c3b = (const float*)d_in[7];
  const float* c4w = (const float*)d_in[8];
  const float* c4b = (const float*)d_in[9];
  const float* f1w = (const float*)d_in[10];
  const float* f1b = (const float*)d_in[11];
  const float* f2w = (const float*)d_in[12];
  const float* f2b = (const float*)d_in[13];
  float* out = (float*)d_out;

  const int B = in_sizes[0] / XLEN;
  const int K = in_sizes[1] / NF;  // 561
  const int nks = (K + 31) / 32;   // 18

  const int items = 7 * nks * 64;
  const size_t aoff = (size_t)items * sizeof(bh8);  // 129024 B
  const size_t abytes = aoff + 16 * sizeof(int);
  const bool pre = ws_size >= abytes;
  bh8* Aarr = (bh8*)d_ws;
  int* bnd = (int*)((char*)d_ws + aoff);

  const size_t smem = (size_t)TOT_E * sizeof(unsigned short);  // 70456 B

  if (pre) {
    hipLaunchKernelGGL(prep_A, dim3((items + 255) / 256), dim3(256), 0, stream,
                       ww, K, nks, Aarr);
    hipLaunchKernelGGL(prep_bounds, dim3(7), dim3(256), 0, stream,
                       ww, K, nks, bnd);
    hipFuncSetAttribute((const void*)fused_convnet<true>,
                        hipFuncAttributeMaxDynamicSharedMemorySize, (int)smem);
    hipLaunchKernelGGL(fused_convnet<true>, dim3(B), dim3(NTH), smem, stream,
                       x, ww, Aarr, bnd, K, nks, c1w, c1b, c2w, c2b, c3w, c3b,
                       c4w, c4b, f1w, f1b, f2w, f2b, out);
  } else {
    hipFuncSetAttribute((const void*)fused_convnet<false>,
                        hipFuncAttributeMaxDynamicSharedMemorySize, (int)smem);
    hipLaunchKernelGGL(fused_convnet<false>, dim3(B), dim3(NTH), smem, stream,
                       x, ww, Aarr, bnd, K, nks, c1w, c1b, c2w, c2b, c3w, c3b,
                       c4w, c4b, f1w, f1b, f2w, f2b, out);
  }
}